// Round 4
// baseline (310.645 us; speedup 1.0000x reference)
//
#include <hip/hip_runtime.h>

#define KS 7
#define NG 16
#define PAD 3
#define EPS 1e-5f
#define NB 8
#define NC 256
#define CR 64
#define NH 64
#define NW 64
#define HW 4096
#define HP 70   // padded height
#define WPS 72  // padded row stride (70 used + 2 align slack)
#define KK 49

// ---------------- kernel 1: zero-padded copy of x ----------------
__global__ __launch_bounds__(256) void k_pad(const float* __restrict__ x,
                                             float* __restrict__ xpad) {
    int idx = blockIdx.x * 256 + threadIdx.x;   // total = NB*NC*HP*WPS
    int wp = idx % WPS;
    int hp = (idx / WPS) % HP;
    int bc = idx / (WPS * HP);
    float v = 0.f;
    if (wp >= PAD && wp < NW + PAD && hp >= PAD && hp < NH + PAD)
        v = x[(size_t)bc * HW + (hp - PAD) * NW + (wp - PAD)];
    xpad[idx] = v;
}

// ---------------- kernel 2: weight prep (weight-norm + BN fold) ----------------
__global__ __launch_bounds__(64) void k_prep(
    const float* __restrict__ v_reduce, const float* __restrict__ g_reduce,
    const float* __restrict__ b_reduce, const float* __restrict__ bn_gamma,
    const float* __restrict__ bn_beta, const float* __restrict__ bn_mean,
    const float* __restrict__ bn_var, const float* __restrict__ v_span,
    const float* __restrict__ g_span, const float* __restrict__ b_span,
    float* __restrict__ wrT, float* __restrict__ br,
    float* __restrict__ wsT, float* __restrict__ bs) {
    int row = blockIdx.x;   // 0..847
    int t = threadIdx.x;    // 0..63
    if (row < CR) {
        int o = row;
        float s = 0.f;
        #pragma unroll
        for (int i = 0; i < 4; i++) {
            float v = v_reduce[o * NC + t + 64 * i];
            s += v * v;
        }
        #pragma unroll
        for (int m = 32; m >= 1; m >>= 1) s += __shfl_xor(s, m);
        float norm = sqrtf(s);
        float bnscale = bn_gamma[o] * rsqrtf(bn_var[o] + EPS);
        float wscale = g_reduce[o] / norm * bnscale;
        #pragma unroll
        for (int i = 0; i < 4; i++) {
            int c = t + 64 * i;
            wrT[c * CR + o] = v_reduce[o * NC + c] * wscale;
        }
        if (t == 0) br[o] = (b_reduce[o] - bn_mean[o]) * bnscale + bn_beta[o];
    } else {
        int o = row - CR;   // 0..783
        float v = v_span[o * CR + t];
        float s = v * v;
        #pragma unroll
        for (int m = 32; m >= 1; m >>= 1) s += __shfl_xor(s, m);
        float norm = sqrtf(s);
        float wscale = g_span[o] / norm;
        int kk = o / NG, g = o % NG;
        wsT[(g * CR + t) * KK + kk] = v * wscale;
        if (t == 0) bs[g * KK + kk] = b_span[o];
    }
}

// ---------------- kernel 3: reduce 1x1 conv + BN + ReLU ----------------
__global__ __launch_bounds__(256) void k_reduce(const float* __restrict__ x,
                                                const float* __restrict__ wrT,
                                                const float* __restrict__ br,
                                                float* __restrict__ r) {
    int b = blockIdx.y;
    int p = blockIdx.x * 256 + threadIdx.x;
    const float* xb = x + (size_t)b * NC * HW + p;
    float acc[CR];
    #pragma unroll
    for (int o = 0; o < CR; o++) acc[o] = 0.f;
    for (int c = 0; c < NC; c++) {
        float xv = xb[(size_t)c * HW];
        const float* wc = wrT + c * CR;   // wave-uniform -> s_load
        #pragma unroll
        for (int o = 0; o < CR; o++) acc[o] += wc[o] * xv;
    }
    float* rb = r + (size_t)b * CR * HW + p;
    #pragma unroll
    for (int o = 0; o < CR; o++) {
        float v = acc[o] + br[o];
        rb[(size_t)o * HW] = fmaxf(v, 0.f);
    }
}

// ---------------- kernel 4: fused span conv + involution ----------------
__global__ __launch_bounds__(256) void k_span_inv(const float* __restrict__ r,
                                                  const float* __restrict__ wsT,
                                                  const float* __restrict__ bs,
                                                  const float* __restrict__ xpad,
                                                  float* __restrict__ out) {
    int chunk = blockIdx.x;   // 0..15
    int g = blockIdx.y;       // 0..15
    int b = blockIdx.z;       // 0..7
    int p = chunk * 256 + threadIdx.x;   // pixel 0..4095
    int h = p >> 6, w = p & 63;

    // phase A: per-pixel span kernel, kv[kk] = sum_c wsT[g][c][kk] * r[b][c][p] + bias
    float kv[KK];
    const float* bsp = bs + g * KK;      // uniform
    #pragma unroll
    for (int k = 0; k < KK; k++) kv[k] = bsp[k];
    const float* rb = r + (size_t)b * CR * HW + p;
    const float* wg = wsT + (size_t)g * CR * KK;   // uniform -> SGPR loads
    #pragma unroll 2
    for (int c = 0; c < CR; c++) {
        float rv = rb[(size_t)c * HW];
        const float* wc = wg + c * KK;
        #pragma unroll
        for (int k = 0; k < KK; k++) kv[k] += wc[k] * rv;
    }

    // phase B: involution, 16 channels of this group, 49 taps each
    const float* xb = xpad + ((size_t)(b * NC + g * 16) * HP + h) * WPS + w;
    float* ob = out + (size_t)(b * NC + g * 16) * HW + p;
    for (int d = 0; d < 16; d++) {
        const float* xd = xb + (size_t)d * HP * WPS;
        float acc = 0.f;
        #pragma unroll
        for (int ki = 0; ki < KS; ki++)
            #pragma unroll
            for (int kj = 0; kj < KS; kj++)
                acc += xd[ki * WPS + kj] * kv[ki * KS + kj];
        ob[(size_t)d * HW] = acc;
    }
}

extern "C" void kernel_launch(void* const* d_in, const int* in_sizes, int n_in,
                              void* d_out, int out_size, void* d_ws, size_t ws_size,
                              hipStream_t stream) {
    const float* x        = (const float*)d_in[0];
    const float* v_reduce = (const float*)d_in[1];
    const float* g_reduce = (const float*)d_in[2];
    const float* b_reduce = (const float*)d_in[3];
    const float* bn_gamma = (const float*)d_in[4];
    const float* bn_beta  = (const float*)d_in[5];
    const float* bn_mean  = (const float*)d_in[6];
    const float* bn_var   = (const float*)d_in[7];
    const float* v_span   = (const float*)d_in[8];
    const float* g_span   = (const float*)d_in[9];
    const float* b_span   = (const float*)d_in[10];
    float* out = (float*)d_out;

    float* ws = (float*)d_ws;
    // workspace layout (floats)
    size_t off = 0;
    float* xpad = ws + off; off += (size_t)NB * NC * HP * WPS;   // 10,321,920
    float* r    = ws + off; off += (size_t)NB * CR * HW;          // 2,097,152
    float* wrT  = ws + off; off += (size_t)NC * CR;               // 16,384
    float* br   = ws + off; off += CR;                            // 64
    float* wsT  = ws + off; off += (size_t)NG * CR * KK;          // 50,176
    float* bs   = ws + off; off += (size_t)NG * KK;               // 784

    // 1. pad
    int pad_elems = NB * NC * HP * WPS;
    k_pad<<<pad_elems / 256, 256, 0, stream>>>(x, xpad);
    // 2. weight prep
    k_prep<<<CR + KK * NG, 64, 0, stream>>>(v_reduce, g_reduce, b_reduce,
                                            bn_gamma, bn_beta, bn_mean, bn_var,
                                            v_span, g_span, b_span,
                                            wrT, br, wsT, bs);
    // 3. reduce conv
    dim3 gr(HW / 256, NB);
    k_reduce<<<gr, 256, 0, stream>>>(x, wrT, br, r);
    // 4. fused span + involution
    dim3 gs(HW / 256, NG, NB);
    k_span_inv<<<gs, 256, 0, stream>>>(r, wsT, bs, xpad, out);
}

// Round 5
// 264.471 us; speedup vs baseline: 1.1746x; 1.1746x over previous
//
#include <hip/hip_runtime.h>

#define KS 7
#define NG 16
#define PAD 3
#define EPS 1e-5f
#define NB 8
#define NC 256
#define CR 64
#define NH 64
#define NW 64
#define HW 4096
#define HPAD 70          // padded spatial extent (64 + 2*3)
#define KK 49
#define ND 16            // channels per group

// xt layout: [b][g][hp][wp][d16], d innermost (float4-friendly)
#define XT_G   ((size_t)HPAD * HPAD * ND)          // 78400
#define XT_B   ((size_t)NG * XT_G)                 // 1254400

// ---------------- kernel 1: padded transpose x -> xt[b][g][hp][wp][d] ----------------
__global__ __launch_bounds__(256) void k_pad_t(const float* __restrict__ x,
                                               float* __restrict__ xt) {
    int idx = blockIdx.x * 256 + threadIdx.x;     // total = NB*NG*70*70*4 (float4s)
    int dq = idx & 3;
    int t = idx >> 2;
    int wp = t % HPAD;
    int t2 = t / HPAD;
    int hp = t2 % HPAD;
    int t3 = t2 / HPAD;
    int g = t3 % NG;
    int b = t3 / NG;

    float4 v = make_float4(0.f, 0.f, 0.f, 0.f);
    int h = hp - PAD, w = wp - PAD;
    if (h >= 0 && h < NH && w >= 0 && w < NW) {
        const float* src = x + ((size_t)(b * NC + g * ND + dq * 4) * HW) + h * NW + w;
        v.x = src[0 * HW];
        v.y = src[1 * HW];
        v.z = src[2 * HW];
        v.w = src[3 * HW];
    }
    float4* dst = (float4*)(xt + (size_t)b * XT_B + (size_t)g * XT_G
                            + ((size_t)hp * HPAD + wp) * ND);
    dst[dq] = v;
}

// ---------------- kernel 2: weight prep (weight-norm + BN fold) ----------------
__global__ __launch_bounds__(64) void k_prep(
    const float* __restrict__ v_reduce, const float* __restrict__ g_reduce,
    const float* __restrict__ b_reduce, const float* __restrict__ bn_gamma,
    const float* __restrict__ bn_beta, const float* __restrict__ bn_mean,
    const float* __restrict__ bn_var, const float* __restrict__ v_span,
    const float* __restrict__ g_span, const float* __restrict__ b_span,
    float* __restrict__ wrT, float* __restrict__ br,
    float* __restrict__ wsT, float* __restrict__ bs) {
    int row = blockIdx.x;   // 0..847
    int t = threadIdx.x;    // 0..63
    if (row < CR) {
        int o = row;
        float s = 0.f;
        #pragma unroll
        for (int i = 0; i < 4; i++) {
            float v = v_reduce[o * NC + t + 64 * i];
            s += v * v;
        }
        #pragma unroll
        for (int m = 32; m >= 1; m >>= 1) s += __shfl_xor(s, m);
        float norm = sqrtf(s);
        float bnscale = bn_gamma[o] * rsqrtf(bn_var[o] + EPS);
        float wscale = g_reduce[o] / norm * bnscale;
        #pragma unroll
        for (int i = 0; i < 4; i++) {
            int c = t + 64 * i;
            wrT[c * CR + o] = v_reduce[o * NC + c] * wscale;
        }
        if (t == 0) br[o] = (b_reduce[o] - bn_mean[o]) * bnscale + bn_beta[o];
    } else {
        int o = row - CR;   // 0..783  (span out channel, layout o = (ki*K+kj)*G + g)
        float v = v_span[o * CR + t];
        float s = v * v;
        #pragma unroll
        for (int m = 32; m >= 1; m >>= 1) s += __shfl_xor(s, m);
        float norm = sqrtf(s);
        float wscale = g_span[o] / norm;
        int kk = o / NG, g = o % NG;
        wsT[(g * CR + t) * KK + kk] = v * wscale;
        if (t == 0) bs[g * KK + kk] = b_span[o];
    }
}

// ---------------- kernel 3: reduce 1x1 conv + BN + ReLU ----------------
// 16 outputs per thread, 4 output-chunks -> 512 blocks (8 waves/CU)
__global__ __launch_bounds__(256) void k_reduce(const float* __restrict__ x,
                                                const float* __restrict__ wrT,
                                                const float* __restrict__ br,
                                                float* __restrict__ r) {
    int oc = blockIdx.y;               // 0..3
    int b = blockIdx.z;
    int p = blockIdx.x * 256 + threadIdx.x;
    const float* xb = x + (size_t)b * NC * HW + p;
    float acc[16];
    #pragma unroll
    for (int o = 0; o < 16; o++) acc[o] = 0.f;
    const float* w0 = wrT + oc * 16;
    #pragma unroll 4
    for (int c = 0; c < NC; c++) {
        float xv = xb[(size_t)c * HW];
        const float* wc = w0 + c * CR;   // wave-uniform -> s_load
        #pragma unroll
        for (int o = 0; o < 16; o++) acc[o] += wc[o] * xv;
    }
    float* rb = r + (size_t)b * CR * HW + (size_t)oc * 16 * HW + p;
    const float* brp = br + oc * 16;
    #pragma unroll
    for (int o = 0; o < 16; o++) {
        float v = acc[o] + brp[o];
        rb[(size_t)o * HW] = fmaxf(v, 0.f);
    }
}

// ---------------- kernel 4: fused span conv + involution ----------------
__global__ __launch_bounds__(256) void k_span_inv(const float* __restrict__ r,
                                                  const float* __restrict__ wsT,
                                                  const float* __restrict__ bs,
                                                  const float* __restrict__ xt,
                                                  float* __restrict__ out) {
    int chunk = blockIdx.x;   // 0..15
    int g = blockIdx.y;       // 0..15
    int b = blockIdx.z;       // 0..7
    int p = chunk * 256 + threadIdx.x;   // pixel 0..4095
    int h = p >> 6, w = p & 63;

    // phase A: per-pixel span kernel, kv[kk] = sum_c wsT[g][c][kk] * r[b][c][p] + bias
    float kv[KK];
    const float* bsp = bs + g * KK;      // uniform
    #pragma unroll
    for (int k = 0; k < KK; k++) kv[k] = bsp[k];
    const float* rb = r + (size_t)b * CR * HW + p;
    const float* wg = wsT + (size_t)g * CR * KK;   // uniform -> SGPR loads
    #pragma unroll 2
    for (int c = 0; c < CR; c++) {
        float rv = rb[(size_t)c * HW];
        const float* wc = wg + c * KK;
        #pragma unroll
        for (int k = 0; k < KK; k++) kv[k] += wc[k] * rv;
    }

    // phase B: involution from xt[b][g][h+ki][w+kj][d], two halves of 8 channels
    const float* xg = xt + (size_t)b * XT_B + (size_t)g * XT_G;
    float* ob = out + (size_t)(b * NC + g * ND) * HW + p;
    #pragma unroll
    for (int half = 0; half < 2; half++) {
        int d0 = half * 8;
        float acc[8];
        #pragma unroll
        for (int j = 0; j < 8; j++) acc[j] = 0.f;
        #pragma unroll
        for (int ki = 0; ki < KS; ki++) {
            const float* xrow = xg + ((size_t)(h + ki) * HPAD + w) * ND + d0;
            #pragma unroll
            for (int kj = 0; kj < KS; kj++) {
                const float4* q = (const float4*)(xrow + kj * ND);
                float4 a = q[0];
                float4 c4 = q[1];
                float kvv = kv[ki * KS + kj];
                acc[0] += a.x * kvv;
                acc[1] += a.y * kvv;
                acc[2] += a.z * kvv;
                acc[3] += a.w * kvv;
                acc[4] += c4.x * kvv;
                acc[5] += c4.y * kvv;
                acc[6] += c4.z * kvv;
                acc[7] += c4.w * kvv;
            }
        }
        #pragma unroll
        for (int j = 0; j < 8; j++)
            ob[(size_t)(d0 + j) * HW] = acc[j];
    }
}

extern "C" void kernel_launch(void* const* d_in, const int* in_sizes, int n_in,
                              void* d_out, int out_size, void* d_ws, size_t ws_size,
                              hipStream_t stream) {
    const float* x        = (const float*)d_in[0];
    const float* v_reduce = (const float*)d_in[1];
    const float* g_reduce = (const float*)d_in[2];
    const float* b_reduce = (const float*)d_in[3];
    const float* bn_gamma = (const float*)d_in[4];
    const float* bn_beta  = (const float*)d_in[5];
    const float* bn_mean  = (const float*)d_in[6];
    const float* bn_var   = (const float*)d_in[7];
    const float* v_span   = (const float*)d_in[8];
    const float* g_span   = (const float*)d_in[9];
    const float* b_span   = (const float*)d_in[10];
    float* out = (float*)d_out;

    float* ws = (float*)d_ws;
    size_t off = 0;
    float* xt   = ws + off; off += (size_t)NB * XT_B;             // 10,035,200
    float* r    = ws + off; off += (size_t)NB * CR * HW;          // 2,097,152
    float* wrT  = ws + off; off += (size_t)NC * CR;               // 16,384
    float* br   = ws + off; off += CR;                            // 64
    float* wsT  = ws + off; off += (size_t)NG * CR * KK;          // 50,176
    float* bs   = ws + off; off += (size_t)NG * KK;               // 784

    // 1. padded transpose
    int padt_threads = NB * NG * HPAD * HPAD * 4;   // float4s of d
    k_pad_t<<<padt_threads / 256, 256, 0, stream>>>(x, xt);
    // 2. weight prep
    k_prep<<<CR + KK * NG, 64, 0, stream>>>(v_reduce, g_reduce, b_reduce,
                                            bn_gamma, bn_beta, bn_mean, bn_var,
                                            v_span, g_span, b_span,
                                            wrT, br, wsT, bs);
    // 3. reduce conv (16 outputs/thread, 4 output chunks)
    dim3 gr(HW / 256, 4, NB);
    k_reduce<<<gr, 256, 0, stream>>>(x, wrT, br, r);
    // 4. fused span + involution
    dim3 gs(HW / 256, NG, NB);
    k_span_inv<<<gs, 256, 0, stream>>>(r, wsT, bs, xt, out);
}

// Round 9
// 215.235 us; speedup vs baseline: 1.4433x; 1.2288x over previous
//
#include <hip/hip_runtime.h>
#include <hip/hip_bf16.h>

#define KS 7
#define NG 16
#define PAD 3
#define EPS 1e-5f
#define NB 8
#define NC 256
#define CR 64
#define NH 64
#define NW 64
#define HW 4096
#define HPAD 70          // padded spatial extent (64 + 2*3)
#define KK 49
#define ND 16            // channels per group

// xt layout: [b][g][hp][wp][d16], d innermost (float4-friendly)
#define XT_G   ((size_t)HPAD * HPAD * ND)          // 78400
#define XT_B   ((size_t)NG * XT_G)                 // 1254400

typedef short bf16x8 __attribute__((ext_vector_type(8)));
typedef float f32x4 __attribute__((ext_vector_type(4)));

static __device__ __forceinline__ ushort f2bf(float v) {
    __hip_bfloat16 hb = __float2bfloat16(v);
    return *reinterpret_cast<ushort*>(&hb);
}

// ---------------- kernel 1: padded transpose x -> xt[b][g][hp][wp][d] (fp32) ----------------
__global__ __launch_bounds__(256) void k_pad_t(const float* __restrict__ x,
                                               float* __restrict__ xt) {
    int idx = blockIdx.x * 256 + threadIdx.x;     // total = NB*NG*70*70*4 (float4s)
    int dq = idx & 3;
    int t = idx >> 2;
    int wp = t % HPAD;
    int t2 = t / HPAD;
    int hp = t2 % HPAD;
    int t3 = t2 / HPAD;
    int g = t3 % NG;
    int b = t3 / NG;

    float4 v = make_float4(0.f, 0.f, 0.f, 0.f);
    int h = hp - PAD, w = wp - PAD;
    if (h >= 0 && h < NH && w >= 0 && w < NW) {
        const float* src = x + ((size_t)(b * NC + g * ND + dq * 4) * HW) + h * NW + w;
        v.x = src[0 * HW];
        v.y = src[1 * HW];
        v.z = src[2 * HW];
        v.w = src[3 * HW];
    }
    float4* dst = (float4*)(xt + (size_t)b * XT_B + (size_t)g * XT_G
                            + ((size_t)hp * HPAD + wp) * ND);
    dst[dq] = v;
}

// ---------------- kernel 2: weight prep (weight-norm + BN fold) ----------------
// blocks 0..63: reduce weights -> wrT fp32 [c][64 o], br fp32
// blocks 64..1087: span weights -> ws2 bf16 [g][kk(64 pad)][c64], bs fp32 [g][64]
__global__ __launch_bounds__(64) void k_prep(
    const float* __restrict__ v_reduce, const float* __restrict__ g_reduce,
    const float* __restrict__ b_reduce, const float* __restrict__ bn_gamma,
    const float* __restrict__ bn_beta, const float* __restrict__ bn_mean,
    const float* __restrict__ bn_var, const float* __restrict__ v_span,
    const float* __restrict__ g_span, const float* __restrict__ b_span,
    float* __restrict__ wrT, float* __restrict__ br,
    ushort* __restrict__ ws2, float* __restrict__ bs) {
    int row = blockIdx.x;
    int t = threadIdx.x;    // 0..63
    if (row < CR) {
        int o = row;
        float s = 0.f;
        #pragma unroll
        for (int i = 0; i < 4; i++) {
            float v = v_reduce[o * NC + t + 64 * i];
            s += v * v;
        }
        #pragma unroll
        for (int m = 32; m >= 1; m >>= 1) s += __shfl_xor(s, m);
        float norm = sqrtf(s);
        float bnscale = bn_gamma[o] * rsqrtf(bn_var[o] + EPS);
        float wscale = g_reduce[o] / norm * bnscale;
        #pragma unroll
        for (int i = 0; i < 4; i++) {
            int c = t + 64 * i;
            wrT[c * CR + o] = v_reduce[o * NC + c] * wscale;
        }
        if (t == 0) br[o] = (b_reduce[o] - bn_mean[o]) * bnscale + bn_beta[o];
    } else {
        int o2 = row - CR;            // 0..1023
        int g = o2 >> 6, kk = o2 & 63;
        ushort wv = 0;
        float bval = 0.f;
        if (kk < KK) {
            int o = kk * NG + g;      // span out channel (k j g) layout
            float v = v_span[o * CR + t];
            float s = v * v;
            #pragma unroll
            for (int m = 32; m >= 1; m >>= 1) s += __shfl_xor(s, m);
            float w = v * (g_span[o] / sqrtf(s));
            wv = f2bf(w);
            bval = b_span[o];
        }
        ws2[(((size_t)g << 6) + kk) * 64 + t] = wv;
        if (t == 0) bs[(g << 6) + kk] = bval;
    }
}

// ---------------- kernel 3: reduce 1x1 conv + BN + ReLU -> rt bf16 [b][p][c] ----------------
__global__ __launch_bounds__(256) void k_reduce(const float* __restrict__ x,
                                                const float* __restrict__ wrT,
                                                const float* __restrict__ br,
                                                ushort* __restrict__ rt) {
    int oc = blockIdx.y;               // 0..3
    int b = blockIdx.z;
    int p = blockIdx.x * 256 + threadIdx.x;
    const float* xb = x + (size_t)b * NC * HW + p;
    float acc[16];
    #pragma unroll
    for (int o = 0; o < 16; o++) acc[o] = 0.f;
    const float* w0 = wrT + oc * 16;
    #pragma unroll 4
    for (int c = 0; c < NC; c++) {
        float xv = xb[(size_t)c * HW];
        const float* wc = w0 + c * CR;   // wave-uniform -> s_load
        #pragma unroll
        for (int o = 0; o < 16; o++) acc[o] += wc[o] * xv;
    }
    const float* brp = br + oc * 16;
    uint pk[8];
    #pragma unroll
    for (int j = 0; j < 8; j++) {
        float v0 = fmaxf(acc[2 * j] + brp[2 * j], 0.f);
        float v1 = fmaxf(acc[2 * j + 1] + brp[2 * j + 1], 0.f);
        pk[j] = (uint)f2bf(v0) | ((uint)f2bf(v1) << 16);
    }
    // rt[b][p][oc*16 .. +16), byte offset = p*128 + oc*32 : 16B aligned
    uint4* dst = (uint4*)(rt + (((size_t)b * HW + p) << 6) + (oc << 4));
    dst[0] = make_uint4(pk[0], pk[1], pk[2], pk[3]);
    dst[1] = make_uint4(pk[4], pk[5], pk[6], pk[7]);
}

// ---------------- kernel 4: MFMA span GEMM (-> LDS) + involution ----------------
// block: (h row, g, b). 256 threads = 4 waves. Per block: 64 pixels.
__global__ __launch_bounds__(256) void k_span_inv(const ushort* __restrict__ rt,
                                                  const ushort* __restrict__ ws2,
                                                  const float* __restrict__ bs,
                                                  const float* __restrict__ xt,
                                                  float* __restrict__ out) {
    __shared__ float kv_lds[64][65];   // stride 65: phase-B reads conflict-free
    int h = blockIdx.x, g = blockIdx.y, b = blockIdx.z;
    int tid = threadIdx.x;
    int lane = tid & 63, wv = tid >> 6;

    // ---- phase A: kv[64 p][64 kk(pad)] = rt[p][c] . ws2[kk][c]^T + bs ----
    int m = lane & 15, kb = lane >> 4;   // tile-row / k-block per m89/m92 layout
    const ushort* wg = ws2 + ((size_t)g << 12);          // g*64*64
    bf16x8 bfrag[4][2];
    #pragma unroll
    for (int n = 0; n < 4; n++)
        #pragma unroll
        for (int ks = 0; ks < 2; ks++)
            bfrag[n][ks] = *(const bf16x8*)(wg + (((n * 16 + m) << 6) + ks * 32 + kb * 8));
    f32x4 acc[4];
    #pragma unroll
    for (int n = 0; n < 4; n++) {
        float bv = bs[(g << 6) + n * 16 + m];
        acc[n] = (f32x4){bv, bv, bv, bv};
    }
    const ushort* ra = rt + ((((size_t)b << 12) + (h << 6) + (wv << 4) + m) << 6);
    #pragma unroll
    for (int ks = 0; ks < 2; ks++) {
        bf16x8 afrag = *(const bf16x8*)(ra + ks * 32 + kb * 8);
        #pragma unroll
        for (int n = 0; n < 4; n++)
            acc[n] = __builtin_amdgcn_mfma_f32_16x16x32_bf16(afrag, bfrag[n][ks], acc[n], 0, 0, 0);
    }
    // C/D: col = lane&15 (kk), row = (lane>>4)*4 + reg (pixel)
    #pragma unroll
    for (int n = 0; n < 4; n++)
        #pragma unroll
        for (int ri = 0; ri < 4; ri++)
            kv_lds[(wv << 4) + (kb << 2) + ri][n * 16 + m] = acc[n][ri];
    __syncthreads();

    // ---- phase B: involution, thread = (pixel pl, d-quad q), fp32 exact ----
    int q = tid & 3, pl = tid >> 2;      // pl = w coordinate (64 pixels = row h)
    const float* xg = xt + (size_t)b * XT_B + (size_t)g * XT_G + (q << 2);
    float a0 = 0.f, a1 = 0.f, a2 = 0.f, a3 = 0.f;
    #pragma unroll
    for (int ki = 0; ki < KS; ki++) {
        const float* xrow = xg + ((size_t)(h + ki) * HPAD + pl) * ND;
        #pragma unroll
        for (int kj = 0; kj < KS; kj++) {
            float kvv = kv_lds[pl][ki * KS + kj];
            float4 xv = *(const float4*)(xrow + kj * ND);
            a0 += xv.x * kvv;
            a1 += xv.y * kvv;
            a2 += xv.z * kvv;
            a3 += xv.w * kvv;
        }
    }
    float* ob = out + (((size_t)(b * NC + (g << 4) + (q << 2))) << 12) + (h << 6) + pl;
    ob[0] = a0;
    ob[HW] = a1;
    ob[2 * HW] = a2;
    ob[3 * HW] = a3;
}

extern "C" void kernel_launch(void* const* d_in, const int* in_sizes, int n_in,
                              void* d_out, int out_size, void* d_ws, size_t ws_size,
                              hipStream_t stream) {
    const float* x        = (const float*)d_in[0];
    const float* v_reduce = (const float*)d_in[1];
    const float* g_reduce = (const float*)d_in[2];
    const float* b_reduce = (const float*)d_in[3];
    const float* bn_gamma = (const float*)d_in[4];
    const float* bn_beta  = (const float*)d_in[5];
    const float* bn_mean  = (const float*)d_in[6];
    const float* bn_var   = (const float*)d_in[7];
    const float* v_span   = (const float*)d_in[8];
    const float* g_span   = (const float*)d_in[9];
    const float* b_span   = (const float*)d_in[10];
    float* out = (float*)d_out;

    float* ws = (float*)d_ws;
    size_t off = 0;
    float* xt    = ws + off; off += (size_t)NB * XT_B;          // 10,035,200 f
    ushort* rt   = (ushort*)(ws + off); off += (size_t)NB * HW * CR / 2;  // bf16 [b][p][c]
    float* wrT   = ws + off; off += (size_t)NC * CR;            // 16,384 f
    float* br    = ws + off; off += CR;                         // 64 f
    ushort* ws2  = (ushort*)(ws + off); off += (size_t)NG * 64 * 64 / 2;  // bf16
    float* bs    = ws + off; off += (size_t)NG * 64;            // 1024 f

    // 1. padded transpose (fp32)
    int padt_threads = NB * NG * HPAD * HPAD * 4;
    k_pad_t<<<padt_threads / 256, 256, 0, stream>>>(x, xt);
    // 2. weight prep
    k_prep<<<CR + NG * 64, 64, 0, stream>>>(v_reduce, g_reduce, b_reduce,
                                            bn_gamma, bn_beta, bn_mean, bn_var,
                                            v_span, g_span, b_span,
                                            wrT, br, ws2, bs);
    // 3. reduce conv -> bf16 rt
    dim3 gr(HW / 256, 4, NB);
    k_reduce<<<gr, 256, 0, stream>>>(x, wrT, br, rt);
    // 4. MFMA span + involution
    dim3 gs(NH, NG, NB);
    k_span_inv<<<gs, 256, 0, stream>>>(rt, ws2, bs, xt, out);
}